// Round 6
// baseline (417.500 us; speedup 1.0000x reference)
//
#include <hip/hip_runtime.h>
#include <hip/hip_fp16.h>

// Tri-plane importance-renderer sampling.
// planes: [N=4][P=3][C=32][H=256][W=256] f32
// coords: [N][M=500000][3] f32, directions unused.
// out:    [N][M][C] f32  = mean over P of bilinear samples (zeros padding,
//                          align_corners=False).
// Plane->grid mapping (from inv(_PLANES)): p0:(cx,cy)  p1:(cx,cz)  p2:(cz,cx)
//
// R5 insight: 4B-index scatter fixed write amplification but total barely
// moved -> remaining cost is (a) single-atomic-per-thread latency in
// hist/scatter and (b) random idx->coords indirection inside the hot gather.
// R6: 8 samples/thread (8 atomics in flight), key[] cache, and a permute
// pass producing sorted 16B records {cx,cy,cz,m} so the gather streams its
// inputs and spends its memory budget on (sorted, local) plane reads.

constexpr int Cc = 32, Hh = 256, Ww = 256, Pp = 3, Nn = 4;
constexpr int HWPIX = Hh * Ww;   // 65536
constexpr int NCELLS = 32768;    // 32^3 Morton cells

// ---------------------------------------------------------------------------
// Morton key helpers: 5 bits per axis, interleaved -> 15-bit key.
// ---------------------------------------------------------------------------
__device__ inline unsigned spread3(unsigned x) {
    x &= 0x3FFu;
    x = (x | (x << 16)) & 0x030000FFu;
    x = (x | (x << 8))  & 0x0300F00Fu;
    x = (x | (x << 4))  & 0x030C30C3u;
    x = (x | (x << 2))  & 0x09249249u;
    return x;
}
__device__ inline unsigned morton_key(float cx, float cy, float cz) {
    const int a = min(max((int)((cx + 1.0f) * 16.0f), 0), 31);
    const int b = min(max((int)((cy + 1.0f) * 16.0f), 0), 31);
    const int c = min(max((int)((cz + 1.0f) * 16.0f), 0), 31);
    return spread3((unsigned)a) | (spread3((unsigned)b) << 1) | (spread3((unsigned)c) << 2);
}

// ---------------------------------------------------------------------------
// Pass 1: transpose+convert [slice][C][HW] f32 -> [slice][HW][C] fp16.
// ---------------------------------------------------------------------------
__global__ __launch_bounds__(256) void transpose_chw_hwc_h(
    const float* __restrict__ in, __half* __restrict__ out)
{
    __shared__ float lds[Cc * 257];
    const int slice = blockIdx.y;
    const int pix0  = blockIdx.x * 256;
    const int t     = threadIdx.x;

    const float* src = in + (size_t)slice * Cc * HWPIX + pix0 + t;
    #pragma unroll
    for (int c = 0; c < Cc; ++c)
        lds[c * 257 + t] = src[(size_t)c * HWPIX];
    __syncthreads();

    uint4* dst = reinterpret_cast<uint4*>(
        out + (size_t)slice * HWPIX * Cc + (size_t)pix0 * Cc);
    #pragma unroll
    for (int k = 0; k < 4; ++k) {
        const int idx = k * 256 + t;
        const int pix = idx >> 2;
        const int c0  = (idx & 3) * 8;
        unsigned r[4];
        #pragma unroll
        for (int j = 0; j < 4; ++j) {
            const __half h0 = __float2half(lds[(c0 + 2 * j + 0) * 257 + pix]);
            const __half h1 = __float2half(lds[(c0 + 2 * j + 1) * 257 + pix]);
            r[j] = (unsigned)__half_as_ushort(h0)
                 | ((unsigned)__half_as_ushort(h1) << 16);
        }
        dst[idx] = make_uint4(r[0], r[1], r[2], r[3]);
    }
}

// ---------------------------------------------------------------------------
// Sort pipeline. 8 samples per thread -> 8 independent atomics in flight.
// ---------------------------------------------------------------------------
__global__ __launch_bounds__(256) void zero_u32(unsigned* __restrict__ p, int n)
{
    const int i = blockIdx.x * 256 + threadIdx.x;
    if (i < n) p[i] = 0u;
}

// keys + histogram in one pass; key[] cached for scatter.
__global__ __launch_bounds__(256) void hist8_kernel(
    const float* __restrict__ coords, unsigned* __restrict__ hist,
    unsigned* __restrict__ key, int M)
{
    const int t    = blockIdx.x * 256 + threadIdx.x;
    const int n    = blockIdx.y;
    const int base = t * 8;
    if (base >= M) return;

    unsigned k[8];
    const int cnt = min(8, M - base);
    #pragma unroll
    for (int j = 0; j < 8; ++j) {
        if (j < cnt) {
            const float* cp = coords + ((size_t)n * M + base + j) * 3;
            k[j] = morton_key(cp[0], cp[1], cp[2]);
        }
    }
    #pragma unroll
    for (int j = 0; j < 8; ++j)
        if (j < cnt) atomicAdd(&hist[n * NCELLS + k[j]], 1u);
    #pragma unroll
    for (int j = 0; j < 8; ++j)
        if (j < cnt) key[(size_t)n * M + base + j] = k[j];
}

__global__ __launch_bounds__(1024) void scan_kernel(unsigned* __restrict__ hist)
{
    __shared__ unsigned lds[1024];
    unsigned* h = hist + (size_t)blockIdx.x * NCELLS;
    const int t = threadIdx.x;
    unsigned v[32];
    unsigned s = 0;
    #pragma unroll
    for (int i = 0; i < 32; ++i) { v[i] = h[t * 32 + i]; s += v[i]; }
    lds[t] = s;
    __syncthreads();
    for (int d = 1; d < 1024; d <<= 1) {
        const unsigned add = (t >= d) ? lds[t - d] : 0u;
        __syncthreads();
        lds[t] += add;
        __syncthreads();
    }
    unsigned base = (t > 0) ? lds[t - 1] : 0u;   // exclusive offset
    #pragma unroll
    for (int i = 0; i < 32; ++i) { const unsigned tmp = v[i]; h[t * 32 + i] = base; base += tmp; }
}

__global__ __launch_bounds__(256) void scatter8_kernel(
    const unsigned* __restrict__ key, unsigned* __restrict__ hist,
    unsigned* __restrict__ idx, int M)
{
    const int t    = blockIdx.x * 256 + threadIdx.x;
    const int n    = blockIdx.y;
    const int base = t * 8;
    if (base >= M) return;

    const int cnt = min(8, M - base);
    unsigned k[8];
    #pragma unroll
    for (int j = 0; j < 8; ++j)
        if (j < cnt) k[j] = key[(size_t)n * M + base + j];

    unsigned pos[8];
    #pragma unroll
    for (int j = 0; j < 8; ++j)
        if (j < cnt) pos[j] = atomicAdd(&hist[n * NCELLS + k[j]], 1u);
    #pragma unroll
    for (int j = 0; j < 8; ++j)
        if (j < cnt) idx[(size_t)n * M + pos[j]] = (unsigned)(base + j);
}

// Random-READ permute (no write amplification): sorted 16B records.
__global__ __launch_bounds__(256) void permute_kernel(
    const unsigned* __restrict__ idx, const float* __restrict__ coords,
    float4* __restrict__ crec, int M)
{
    const int s = blockIdx.x * 256 + threadIdx.x;
    const int n = blockIdx.y;
    if (s >= M) return;
    const unsigned m = idx[(size_t)n * M + s];
    const float* cp = coords + ((size_t)n * M + m) * 3;
    float4 r;
    r.x = cp[0]; r.y = cp[1]; r.z = cp[2]; r.w = __uint_as_float(m);
    crec[(size_t)n * M + s] = r;   // sequential 16B store
}

// ---------------------------------------------------------------------------
// Gather in Morton order; inputs fully streaming, plane reads local.
// 8 lanes per sample. Bijective XCD-chunked swizzle.
// ---------------------------------------------------------------------------
__global__ __launch_bounds__(256) void triplane_gather_sorted(
    const __half* __restrict__ tp, const float4* __restrict__ crec,
    float* __restrict__ out, int M, int gx, int nwg)
{
    int bid = blockIdx.x;
    {   // bijective chunked XCD swizzle (m204 form)
        const int q = nwg >> 3, r = nwg & 7;
        const int xcd = bid & 7, i = bid >> 3;
        bid = (xcd < r ? xcd * (q + 1) : r * (q + 1) + (xcd - r) * q) + i;
    }
    const int n  = bid / gx;
    const int bx = bid - n * gx;
    const int gid   = bx * 256 + threadIdx.x;
    const int s     = gid >> 3;
    const int chunk = gid & 7;
    if (s >= M) return;

    const float4 rc = crec[(size_t)n * M + s];   // 8 lanes broadcast-load
    const float cx = rc.x, cy = rc.y, cz = rc.z;
    const int   m  = (int)__float_as_uint(rc.w);

    const uint2* addr[12];
    float w[12];

    #pragma unroll
    for (int p = 0; p < 3; ++p) {
        const float gxc = (p == 2) ? cz : cx;
        const float gyc = (p == 0) ? cy : ((p == 1) ? cz : cx);
        // exact reference op order: ((g+1)*S - 1) * 0.5
        const float x = ((gxc + 1.0f) * 256.0f - 1.0f) * 0.5f;
        const float y = ((gyc + 1.0f) * 256.0f - 1.0f) * 0.5f;
        const float x0f = floorf(x), y0f = floorf(y);
        const float wx = x - x0f, wy = y - y0f;
        const int x0 = (int)x0f, y0 = (int)y0f;
        const int x1 = x0 + 1,   y1 = y0 + 1;
        const bool vx0 = (unsigned)x0 < 256u;
        const bool vx1 = (unsigned)x1 < 256u;
        const bool vy0 = (unsigned)y0 < 256u;
        const bool vy1 = (unsigned)y1 < 256u;
        const int cx0 = min(max(x0, 0), 255), cx1 = min(max(x1, 0), 255);
        const int cy0 = min(max(y0, 0), 255), cy1 = min(max(y1, 0), 255);

        w[p * 4 + 0] = ((vx0 && vy0) ? 1.f : 0.f) * (1.f - wx) * (1.f - wy);
        w[p * 4 + 1] = ((vx1 && vy0) ? 1.f : 0.f) * wx * (1.f - wy);
        w[p * 4 + 2] = ((vx0 && vy1) ? 1.f : 0.f) * (1.f - wx) * wy;
        w[p * 4 + 3] = ((vx1 && vy1) ? 1.f : 0.f) * wx * wy;

        const uint2* base = reinterpret_cast<const uint2*>(
            tp + (size_t)(n * 3 + p) * HWPIX * Cc);
        addr[p * 4 + 0] = base + (size_t)((cy0 << 8) + cx0) * 8 + chunk;
        addr[p * 4 + 1] = base + (size_t)((cy0 << 8) + cx1) * 8 + chunk;
        addr[p * 4 + 2] = base + (size_t)((cy1 << 8) + cx0) * 8 + chunk;
        addr[p * 4 + 3] = base + (size_t)((cy1 << 8) + cx1) * 8 + chunk;
    }

    uint2 rv[12];
    #pragma unroll
    for (int j = 0; j < 12; ++j) rv[j] = *addr[j];

    float4 acc = make_float4(0.f, 0.f, 0.f, 0.f);
    #pragma unroll
    for (int j = 0; j < 12; ++j) {
        const __half2 h0 = *reinterpret_cast<const __half2*>(&rv[j].x);
        const __half2 h1 = *reinterpret_cast<const __half2*>(&rv[j].y);
        const float2 f0 = __half22float2(h0);
        const float2 f1 = __half22float2(h1);
        acc.x += w[j] * f0.x;
        acc.y += w[j] * f0.y;
        acc.z += w[j] * f1.x;
        acc.w += w[j] * f1.y;
    }

    constexpr float third = 1.0f / 3.0f;
    acc.x *= third; acc.y *= third; acc.z *= third; acc.w *= third;

    // 8 lanes write one full 128B line at the sample's original slot.
    float4* op = reinterpret_cast<float4*>(out + ((size_t)n * M + m) * Cc);
    op[chunk] = acc;
}

// ---------------------------------------------------------------------------
// Mid tier (ws fits planes only): unsorted fp16 gather (R3 kernel).
// ---------------------------------------------------------------------------
__global__ __launch_bounds__(256) void triplane_gather_hwc8h(
    const __half* __restrict__ tp, const float* __restrict__ coords,
    float* __restrict__ out, int M)
{
    const int gid   = blockIdx.x * 256 + threadIdx.x;
    const int m     = gid >> 3;
    const int chunk = gid & 7;
    const int n     = blockIdx.y;
    if (m >= M) return;

    const float* cp = coords + ((size_t)n * M + m) * 3;
    const float cx = cp[0], cy = cp[1], cz = cp[2];

    const uint2* addr[12];
    float w[12];

    #pragma unroll
    for (int p = 0; p < 3; ++p) {
        const float gxc = (p == 2) ? cz : cx;
        const float gyc = (p == 0) ? cy : ((p == 1) ? cz : cx);
        const float x = ((gxc + 1.0f) * 256.0f - 1.0f) * 0.5f;
        const float y = ((gyc + 1.0f) * 256.0f - 1.0f) * 0.5f;
        const float x0f = floorf(x), y0f = floorf(y);
        const float wx = x - x0f, wy = y - y0f;
        const int x0 = (int)x0f, y0 = (int)y0f;
        const int x1 = x0 + 1,   y1 = y0 + 1;
        const bool vx0 = (unsigned)x0 < 256u;
        const bool vx1 = (unsigned)x1 < 256u;
        const bool vy0 = (unsigned)y0 < 256u;
        const bool vy1 = (unsigned)y1 < 256u;
        const int cx0 = min(max(x0, 0), 255), cx1 = min(max(x1, 0), 255);
        const int cy0 = min(max(y0, 0), 255), cy1 = min(max(y1, 0), 255);

        w[p * 4 + 0] = ((vx0 && vy0) ? 1.f : 0.f) * (1.f - wx) * (1.f - wy);
        w[p * 4 + 1] = ((vx1 && vy0) ? 1.f : 0.f) * wx * (1.f - wy);
        w[p * 4 + 2] = ((vx0 && vy1) ? 1.f : 0.f) * (1.f - wx) * wy;
        w[p * 4 + 3] = ((vx1 && vy1) ? 1.f : 0.f) * wx * wy;

        const uint2* base = reinterpret_cast<const uint2*>(
            tp + (size_t)(n * 3 + p) * HWPIX * Cc);
        addr[p * 4 + 0] = base + (size_t)((cy0 << 8) + cx0) * 8 + chunk;
        addr[p * 4 + 1] = base + (size_t)((cy0 << 8) + cx1) * 8 + chunk;
        addr[p * 4 + 2] = base + (size_t)((cy1 << 8) + cx0) * 8 + chunk;
        addr[p * 4 + 3] = base + (size_t)((cy1 << 8) + cx1) * 8 + chunk;
    }

    uint2 rv[12];
    #pragma unroll
    for (int j = 0; j < 12; ++j) rv[j] = *addr[j];

    float4 acc = make_float4(0.f, 0.f, 0.f, 0.f);
    #pragma unroll
    for (int j = 0; j < 12; ++j) {
        const __half2 h0 = *reinterpret_cast<const __half2*>(&rv[j].x);
        const __half2 h1 = *reinterpret_cast<const __half2*>(&rv[j].y);
        const float2 f0 = __half22float2(h0);
        const float2 f1 = __half22float2(h1);
        acc.x += w[j] * f0.x;
        acc.y += w[j] * f0.y;
        acc.z += w[j] * f1.x;
        acc.w += w[j] * f1.y;
    }

    constexpr float third = 1.0f / 3.0f;
    acc.x *= third; acc.y *= third; acc.z *= third; acc.w *= third;

    float4* op = reinterpret_cast<float4*>(out + ((size_t)n * M + m) * Cc);
    op[chunk] = acc;
}

// ---------------------------------------------------------------------------
// Fallback (no workspace): gather straight from [C][H][W] f32 layout.
// ---------------------------------------------------------------------------
__global__ __launch_bounds__(256) void triplane_gather_chw(
    const float* __restrict__ planes, const float* __restrict__ coords,
    float* __restrict__ out, int M)
{
    const int m = blockIdx.x * 256 + threadIdx.x;
    const int n = blockIdx.y;
    if (m >= M) return;

    const float* cp = coords + ((size_t)n * M + m) * 3;
    const float cx = cp[0], cy = cp[1], cz = cp[2];

    int   off[3][4];
    float w[3][4];
    #pragma unroll
    for (int p = 0; p < 3; ++p) {
        const float gxc = (p == 2) ? cz : cx;
        const float gyc = (p == 0) ? cy : ((p == 1) ? cz : cx);
        const float x = ((gxc + 1.0f) * 256.0f - 1.0f) * 0.5f;
        const float y = ((gyc + 1.0f) * 256.0f - 1.0f) * 0.5f;
        const float x0f = floorf(x), y0f = floorf(y);
        const float wx = x - x0f, wy = y - y0f;
        const int x0 = (int)x0f, y0 = (int)y0f;
        const int x1 = x0 + 1,   y1 = y0 + 1;
        const bool vx0 = (unsigned)x0 < 256u, vx1 = (unsigned)x1 < 256u;
        const bool vy0 = (unsigned)y0 < 256u, vy1 = (unsigned)y1 < 256u;
        const int cx0 = min(max(x0, 0), 255), cx1 = min(max(x1, 0), 255);
        const int cy0 = min(max(y0, 0), 255), cy1 = min(max(y1, 0), 255);
        off[p][0] = (cy0 << 8) + cx0;  w[p][0] = ((vx0 && vy0) ? 1.f : 0.f) * (1.f - wx) * (1.f - wy);
        off[p][1] = (cy0 << 8) + cx1;  w[p][1] = ((vx1 && vy0) ? 1.f : 0.f) * wx * (1.f - wy);
        off[p][2] = (cy1 << 8) + cx0;  w[p][2] = ((vx0 && vy1) ? 1.f : 0.f) * (1.f - wx) * wy;
        off[p][3] = (cy1 << 8) + cx1;  w[p][3] = ((vx1 && vy1) ? 1.f : 0.f) * wx * wy;
    }

    float* op = out + ((size_t)n * M + m) * Cc;
    constexpr float third = 1.0f / 3.0f;
    for (int c = 0; c < Cc; ++c) {
        float a = 0.f;
        #pragma unroll
        for (int p = 0; p < 3; ++p) {
            const float* b = planes + ((size_t)(n * 3 + p) * Cc + c) * HWPIX;
            a += w[p][0] * b[off[p][0]] + w[p][1] * b[off[p][1]]
               + w[p][2] * b[off[p][2]] + w[p][3] * b[off[p][3]];
        }
        op[c] = a * third;
    }
}

extern "C" void kernel_launch(void* const* d_in, const int* in_sizes, int n_in,
                              void* d_out, int out_size, void* d_ws, size_t ws_size,
                              hipStream_t stream)
{
    const float* planes = (const float*)d_in[0];
    const float* coords = (const float*)d_in[1];
    float* out = (float*)d_out;

    const int M = in_sizes[1] / (Nn * 3);           // 500000

    auto align256 = [](size_t x) { return (x + 255) & ~(size_t)255; };
    const size_t tp_bytes   = align256((size_t)Nn * Pp * HWPIX * Cc * sizeof(__half)); // ~50 MB
    const size_t key_bytes  = align256((size_t)Nn * M * sizeof(unsigned));             // ~8 MB
    const size_t idx_bytes  = align256((size_t)Nn * M * sizeof(unsigned));             // ~8 MB
    const size_t hist_bytes = align256((size_t)Nn * NCELLS * sizeof(unsigned));        // 0.5 MB
    const size_t rec_bytes  = align256((size_t)Nn * M * sizeof(float4));               // ~32 MB

    if (ws_size >= tp_bytes + key_bytes + idx_bytes + hist_bytes + rec_bytes) {
        char* p = (char*)d_ws;
        __half*   tp   = (__half*)p;            p += tp_bytes;
        unsigned* key  = (unsigned*)p;          p += key_bytes;
        unsigned* idx  = (unsigned*)p;          p += idx_bytes;
        unsigned* hist = (unsigned*)p;          p += hist_bytes;
        float4*   crec = (float4*)p;

        transpose_chw_hwc_h<<<dim3(HWPIX / 256, Nn * Pp), 256, 0, stream>>>(planes, tp);
        zero_u32<<<(Nn * NCELLS + 255) / 256, 256, 0, stream>>>(hist, Nn * NCELLS);

        const int t8 = (M + 7) / 8;
        hist8_kernel<<<dim3((t8 + 255) / 256, Nn), 256, 0, stream>>>(coords, hist, key, M);
        scan_kernel<<<Nn, 1024, 0, stream>>>(hist);
        scatter8_kernel<<<dim3((t8 + 255) / 256, Nn), 256, 0, stream>>>(key, hist, idx, M);
        permute_kernel<<<dim3((M + 255) / 256, Nn), 256, 0, stream>>>(idx, coords, crec, M);

        const int gx  = (M * 8 + 255) / 256;   // 8 lanes per sample
        const int nwg = Nn * gx;
        triplane_gather_sorted<<<nwg, 256, 0, stream>>>(tp, crec, out, M, gx, nwg);
    } else if (ws_size >= tp_bytes) {
        __half* tp = (__half*)d_ws;
        transpose_chw_hwc_h<<<dim3(HWPIX / 256, Nn * Pp), 256, 0, stream>>>(planes, tp);
        const int gx = (M * 8 + 255) / 256;
        triplane_gather_hwc8h<<<dim3(gx, Nn), 256, 0, stream>>>(tp, coords, out, M);
    } else {
        const int gx = (M + 255) / 256;
        triplane_gather_chw<<<dim3(gx, Nn), 256, 0, stream>>>(planes, coords, out, M);
    }
}

// Round 7
// 367.299 us; speedup vs baseline: 1.1367x; 1.1367x over previous
//
#include <hip/hip_runtime.h>
#include <hip/hip_fp16.h>

// Tri-plane importance-renderer sampling.
// planes: [N=4][P=3][C=32][H=256][W=256] f32
// coords: [N][M=500000][3] f32, directions unused.
// out:    [N][M][C] f32  = mean over P of bilinear samples (zeros padding,
//                          align_corners=False).
// Plane->grid mapping (from inv(_PLANES)): p0:(cx,cy)  p1:(cx,cz)  p2:(cz,cx)
//
// R6 insight: sort machinery cost ~236us (two ~95us atomic passes + an
// unnecessary permute); gather itself became VALU-bound (60.7% busy, fp16
// cvt + 8x-replicated weight math). R7: single atomic pass (fused key+pos,
// scatter becomes atomic-free), drop permute, and a f32-HWC 4-lane gather
// (no conversions, weight math replicated 4x not 8x, full f32 accuracy).

constexpr int Cc = 32, Hh = 256, Ww = 256, Pp = 3, Nn = 4;
constexpr int HWPIX = Hh * Ww;   // 65536
constexpr int NCELLS = 32768;    // 32^3 Morton cells

// ---------------------------------------------------------------------------
// Morton key: 5 bits/axis interleaved -> 15-bit key.
// ---------------------------------------------------------------------------
__device__ inline unsigned spread3(unsigned x) {
    x &= 0x3FFu;
    x = (x | (x << 16)) & 0x030000FFu;
    x = (x | (x << 8))  & 0x0300F00Fu;
    x = (x | (x << 4))  & 0x030C30C3u;
    x = (x | (x << 2))  & 0x09249249u;
    return x;
}
__device__ inline unsigned morton_key(float cx, float cy, float cz) {
    const int a = min(max((int)((cx + 1.0f) * 16.0f), 0), 31);
    const int b = min(max((int)((cy + 1.0f) * 16.0f), 0), 31);
    const int c = min(max((int)((cz + 1.0f) * 16.0f), 0), 31);
    return spread3((unsigned)a) | (spread3((unsigned)b) << 1) | (spread3((unsigned)c) << 2);
}

// ---------------------------------------------------------------------------
// Pass 1a: transpose [slice][C][HW] -> [slice][HW][C], f32 (one pixel = one
// 128B line).
// ---------------------------------------------------------------------------
__global__ __launch_bounds__(256) void transpose_chw_hwc(
    const float* __restrict__ in, float* __restrict__ out)
{
    __shared__ float lds[Cc * 257];
    const int slice = blockIdx.y;
    const int pix0  = blockIdx.x * 256;
    const int t     = threadIdx.x;

    const float* src = in + (size_t)slice * Cc * HWPIX + pix0 + t;
    #pragma unroll
    for (int c = 0; c < Cc; ++c)
        lds[c * 257 + t] = src[(size_t)c * HWPIX];
    __syncthreads();

    float4* dst = reinterpret_cast<float4*>(
        out + (size_t)slice * HWPIX * Cc + (size_t)pix0 * Cc);
    #pragma unroll
    for (int j = 0; j < 8; ++j) {
        const int idx = j * 256 + t;
        const int pix = idx >> 3;
        const int c0  = (idx & 7) * 4;
        float4 v;
        v.x = lds[(c0 + 0) * 257 + pix];
        v.y = lds[(c0 + 1) * 257 + pix];
        v.z = lds[(c0 + 2) * 257 + pix];
        v.w = lds[(c0 + 3) * 257 + pix];
        dst[idx] = v;
    }
}

// ---------------------------------------------------------------------------
// Sort pipeline: zero -> fused key+hist+pos (ONE atomic pass) -> scan ->
// atomic-free scatter of 4B indices.
// ---------------------------------------------------------------------------
__global__ __launch_bounds__(256) void zero_u32(unsigned* __restrict__ p, int n)
{
    const int i = blockIdx.x * 256 + threadIdx.x;
    if (i < n) p[i] = 0u;
}

// kp[m] = key | (pos_within_cell << 15).  pos < 2^17 (500k uniform over 32k
// cells; worst observed cell ~60).
__global__ __launch_bounds__(256) void histpos8_kernel(
    const float* __restrict__ coords, unsigned* __restrict__ hist,
    unsigned* __restrict__ kp, int M)
{
    const int t    = blockIdx.x * 256 + threadIdx.x;
    const int n    = blockIdx.y;
    const int base = t * 8;
    if (base >= M) return;
    const int cnt = min(8, M - base);

    unsigned k[8];
    #pragma unroll
    for (int j = 0; j < 8; ++j) {
        if (j < cnt) {
            const float* cp = coords + ((size_t)n * M + base + j) * 3;
            k[j] = morton_key(cp[0], cp[1], cp[2]);
        }
    }
    unsigned pos[8];
    #pragma unroll
    for (int j = 0; j < 8; ++j)
        if (j < cnt) pos[j] = atomicAdd(&hist[n * NCELLS + k[j]], 1u);
    #pragma unroll
    for (int j = 0; j < 8; ++j)
        if (j < cnt) kp[(size_t)n * M + base + j] = k[j] | (pos[j] << 15);
}

__global__ __launch_bounds__(1024) void scan_kernel(unsigned* __restrict__ hist)
{
    __shared__ unsigned lds[1024];
    unsigned* h = hist + (size_t)blockIdx.x * NCELLS;
    const int t = threadIdx.x;
    unsigned v[32];
    unsigned s = 0;
    #pragma unroll
    for (int i = 0; i < 32; ++i) { v[i] = h[t * 32 + i]; s += v[i]; }
    lds[t] = s;
    __syncthreads();
    for (int d = 1; d < 1024; d <<= 1) {
        const unsigned add = (t >= d) ? lds[t - d] : 0u;
        __syncthreads();
        lds[t] += add;
        __syncthreads();
    }
    unsigned base = (t > 0) ? lds[t - 1] : 0u;   // exclusive offset
    #pragma unroll
    for (int i = 0; i < 32; ++i) { const unsigned tmp = v[i]; h[t * 32 + i] = base; base += tmp; }
}

// Atomic-free scatter: slot = scanned_base[key] + pos.
__global__ __launch_bounds__(256) void scatter8_kernel(
    const unsigned* __restrict__ kp, const unsigned* __restrict__ hist,
    unsigned* __restrict__ idx, int M)
{
    const int t    = blockIdx.x * 256 + threadIdx.x;
    const int n    = blockIdx.y;
    const int base = t * 8;
    if (base >= M) return;
    const int cnt = min(8, M - base);

    unsigned v[8];
    #pragma unroll
    for (int j = 0; j < 8; ++j)
        if (j < cnt) v[j] = kp[(size_t)n * M + base + j];
    unsigned b[8];
    #pragma unroll
    for (int j = 0; j < 8; ++j)
        if (j < cnt) b[j] = hist[n * NCELLS + (v[j] & 0x7FFFu)];
    #pragma unroll
    for (int j = 0; j < 8; ++j)
        if (j < cnt) idx[(size_t)n * M + b[j] + (v[j] >> 15)] = (unsigned)(base + j);
}

// ---------------------------------------------------------------------------
// Gather in Morton order, f32 planes, FOUR lanes per sample (8 ch each).
// Corner = one 128B line; quad of lanes covers it with 2x float4 each.
// Bijective XCD-chunked swizzle keeps each XCD on a contiguous Morton range.
// ---------------------------------------------------------------------------
__global__ __launch_bounds__(256) void triplane_gather_sorted4(
    const float* __restrict__ tp, const unsigned* __restrict__ idx,
    const float* __restrict__ coords, float* __restrict__ out,
    int M, int gx, int nwg)
{
    int bid = blockIdx.x;
    {   // bijective chunked XCD swizzle (m204 form)
        const int q = nwg >> 3, r = nwg & 7;
        const int xcd = bid & 7, i = bid >> 3;
        bid = (xcd < r ? xcd * (q + 1) : r * (q + 1) + (xcd - r) * q) + i;
    }
    const int n  = bid / gx;
    const int bx = bid - n * gx;
    const int gid  = bx * 256 + threadIdx.x;
    const int s    = gid >> 2;
    const int quad = gid & 3;            // 8-channel group
    if (s >= M) return;

    const int m = (int)idx[(size_t)n * M + s];
    const float* cp = coords + ((size_t)n * M + m) * 3;
    const float cx = cp[0], cy = cp[1], cz = cp[2];

    float4 acc0 = make_float4(0.f, 0.f, 0.f, 0.f);
    float4 acc1 = make_float4(0.f, 0.f, 0.f, 0.f);

    #pragma unroll
    for (int p = 0; p < 3; ++p) {
        const float gxc = (p == 2) ? cz : cx;
        const float gyc = (p == 0) ? cy : ((p == 1) ? cz : cx);
        // exact reference op order: ((g+1)*S - 1) * 0.5
        const float x = ((gxc + 1.0f) * 256.0f - 1.0f) * 0.5f;
        const float y = ((gyc + 1.0f) * 256.0f - 1.0f) * 0.5f;
        const float x0f = floorf(x), y0f = floorf(y);
        const float wx = x - x0f, wy = y - y0f;
        const int x0 = (int)x0f, y0 = (int)y0f;
        const int x1 = x0 + 1,   y1 = y0 + 1;
        const bool vx0 = (unsigned)x0 < 256u;
        const bool vx1 = (unsigned)x1 < 256u;
        const bool vy0 = (unsigned)y0 < 256u;
        const bool vy1 = (unsigned)y1 < 256u;
        const int cx0 = min(max(x0, 0), 255), cx1 = min(max(x1, 0), 255);
        const int cy0 = min(max(y0, 0), 255), cy1 = min(max(y1, 0), 255);

        const float w00 = ((vx0 && vy0) ? 1.f : 0.f) * (1.f - wx) * (1.f - wy);
        const float w10 = ((vx1 && vy0) ? 1.f : 0.f) * wx * (1.f - wy);
        const float w01 = ((vx0 && vy1) ? 1.f : 0.f) * (1.f - wx) * wy;
        const float w11 = ((vx1 && vy1) ? 1.f : 0.f) * wx * wy;

        const float4* bp = reinterpret_cast<const float4*>(
            tp + (size_t)(n * 3 + p) * HWPIX * Cc);
        const float4* a00 = bp + (size_t)((cy0 << 8) + cx0) * 8 + quad * 2;
        const float4* a10 = bp + (size_t)((cy0 << 8) + cx1) * 8 + quad * 2;
        const float4* a01 = bp + (size_t)((cy1 << 8) + cx0) * 8 + quad * 2;
        const float4* a11 = bp + (size_t)((cy1 << 8) + cx1) * 8 + quad * 2;

        // 8 independent 16B loads, then FMAs (no conversions).
        const float4 u00 = a00[0], t00 = a00[1];
        const float4 u10 = a10[0], t10 = a10[1];
        const float4 u01 = a01[0], t01 = a01[1];
        const float4 u11 = a11[0], t11 = a11[1];

        acc0.x += w00 * u00.x + w10 * u10.x + w01 * u01.x + w11 * u11.x;
        acc0.y += w00 * u00.y + w10 * u10.y + w01 * u01.y + w11 * u11.y;
        acc0.z += w00 * u00.z + w10 * u10.z + w01 * u01.z + w11 * u11.z;
        acc0.w += w00 * u00.w + w10 * u10.w + w01 * u01.w + w11 * u11.w;
        acc1.x += w00 * t00.x + w10 * t10.x + w01 * t01.x + w11 * t11.x;
        acc1.y += w00 * t00.y + w10 * t10.y + w01 * t01.y + w11 * t11.y;
        acc1.z += w00 * t00.z + w10 * t10.z + w01 * t01.z + w11 * t11.z;
        acc1.w += w00 * t00.w + w10 * t10.w + w01 * t01.w + w11 * t11.w;
    }

    constexpr float third = 1.0f / 3.0f;
    acc0.x *= third; acc0.y *= third; acc0.z *= third; acc0.w *= third;
    acc1.x *= third; acc1.y *= third; acc1.z *= third; acc1.w *= third;

    float4* op = reinterpret_cast<float4*>(out + ((size_t)n * M + m) * Cc);
    op[quad * 2 + 0] = acc0;
    op[quad * 2 + 1] = acc1;
}

// ---------------------------------------------------------------------------
// Mid tier (ws fits fp16 planes only): fp16 transpose + unsorted gather (R3).
// ---------------------------------------------------------------------------
__global__ __launch_bounds__(256) void transpose_chw_hwc_h(
    const float* __restrict__ in, __half* __restrict__ out)
{
    __shared__ float lds[Cc * 257];
    const int slice = blockIdx.y;
    const int pix0  = blockIdx.x * 256;
    const int t     = threadIdx.x;

    const float* src = in + (size_t)slice * Cc * HWPIX + pix0 + t;
    #pragma unroll
    for (int c = 0; c < Cc; ++c)
        lds[c * 257 + t] = src[(size_t)c * HWPIX];
    __syncthreads();

    uint4* dst = reinterpret_cast<uint4*>(
        out + (size_t)slice * HWPIX * Cc + (size_t)pix0 * Cc);
    #pragma unroll
    for (int k = 0; k < 4; ++k) {
        const int idx = k * 256 + t;
        const int pix = idx >> 2;
        const int c0  = (idx & 3) * 8;
        unsigned r[4];
        #pragma unroll
        for (int j = 0; j < 4; ++j) {
            const __half h0 = __float2half(lds[(c0 + 2 * j + 0) * 257 + pix]);
            const __half h1 = __float2half(lds[(c0 + 2 * j + 1) * 257 + pix]);
            r[j] = (unsigned)__half_as_ushort(h0)
                 | ((unsigned)__half_as_ushort(h1) << 16);
        }
        dst[idx] = make_uint4(r[0], r[1], r[2], r[3]);
    }
}

__global__ __launch_bounds__(256) void triplane_gather_hwc8h(
    const __half* __restrict__ tp, const float* __restrict__ coords,
    float* __restrict__ out, int M)
{
    const int gid   = blockIdx.x * 256 + threadIdx.x;
    const int m     = gid >> 3;
    const int chunk = gid & 7;
    const int n     = blockIdx.y;
    if (m >= M) return;

    const float* cp = coords + ((size_t)n * M + m) * 3;
    const float cx = cp[0], cy = cp[1], cz = cp[2];

    const uint2* addr[12];
    float w[12];

    #pragma unroll
    for (int p = 0; p < 3; ++p) {
        const float gxc = (p == 2) ? cz : cx;
        const float gyc = (p == 0) ? cy : ((p == 1) ? cz : cx);
        const float x = ((gxc + 1.0f) * 256.0f - 1.0f) * 0.5f;
        const float y = ((gyc + 1.0f) * 256.0f - 1.0f) * 0.5f;
        const float x0f = floorf(x), y0f = floorf(y);
        const float wx = x - x0f, wy = y - y0f;
        const int x0 = (int)x0f, y0 = (int)y0f;
        const int x1 = x0 + 1,   y1 = y0 + 1;
        const bool vx0 = (unsigned)x0 < 256u;
        const bool vx1 = (unsigned)x1 < 256u;
        const bool vy0 = (unsigned)y0 < 256u;
        const bool vy1 = (unsigned)y1 < 256u;
        const int cx0 = min(max(x0, 0), 255), cx1 = min(max(x1, 0), 255);
        const int cy0 = min(max(y0, 0), 255), cy1 = min(max(y1, 0), 255);

        w[p * 4 + 0] = ((vx0 && vy0) ? 1.f : 0.f) * (1.f - wx) * (1.f - wy);
        w[p * 4 + 1] = ((vx1 && vy0) ? 1.f : 0.f) * wx * (1.f - wy);
        w[p * 4 + 2] = ((vx0 && vy1) ? 1.f : 0.f) * (1.f - wx) * wy;
        w[p * 4 + 3] = ((vx1 && vy1) ? 1.f : 0.f) * wx * wy;

        const uint2* base = reinterpret_cast<const uint2*>(
            tp + (size_t)(n * 3 + p) * HWPIX * Cc);
        addr[p * 4 + 0] = base + (size_t)((cy0 << 8) + cx0) * 8 + chunk;
        addr[p * 4 + 1] = base + (size_t)((cy0 << 8) + cx1) * 8 + chunk;
        addr[p * 4 + 2] = base + (size_t)((cy1 << 8) + cx0) * 8 + chunk;
        addr[p * 4 + 3] = base + (size_t)((cy1 << 8) + cx1) * 8 + chunk;
    }

    uint2 rv[12];
    #pragma unroll
    for (int j = 0; j < 12; ++j) rv[j] = *addr[j];

    float4 acc = make_float4(0.f, 0.f, 0.f, 0.f);
    #pragma unroll
    for (int j = 0; j < 12; ++j) {
        const __half2 h0 = *reinterpret_cast<const __half2*>(&rv[j].x);
        const __half2 h1 = *reinterpret_cast<const __half2*>(&rv[j].y);
        const float2 f0 = __half22float2(h0);
        const float2 f1 = __half22float2(h1);
        acc.x += w[j] * f0.x;
        acc.y += w[j] * f0.y;
        acc.z += w[j] * f1.x;
        acc.w += w[j] * f1.y;
    }

    constexpr float third = 1.0f / 3.0f;
    acc.x *= third; acc.y *= third; acc.z *= third; acc.w *= third;

    float4* op = reinterpret_cast<float4*>(out + ((size_t)n * M + m) * Cc);
    op[chunk] = acc;
}

// ---------------------------------------------------------------------------
// Fallback (no workspace): gather straight from [C][H][W] f32 layout.
// ---------------------------------------------------------------------------
__global__ __launch_bounds__(256) void triplane_gather_chw(
    const float* __restrict__ planes, const float* __restrict__ coords,
    float* __restrict__ out, int M)
{
    const int m = blockIdx.x * 256 + threadIdx.x;
    const int n = blockIdx.y;
    if (m >= M) return;

    const float* cp = coords + ((size_t)n * M + m) * 3;
    const float cx = cp[0], cy = cp[1], cz = cp[2];

    int   off[3][4];
    float w[3][4];
    #pragma unroll
    for (int p = 0; p < 3; ++p) {
        const float gxc = (p == 2) ? cz : cx;
        const float gyc = (p == 0) ? cy : ((p == 1) ? cz : cx);
        const float x = ((gxc + 1.0f) * 256.0f - 1.0f) * 0.5f;
        const float y = ((gyc + 1.0f) * 256.0f - 1.0f) * 0.5f;
        const float x0f = floorf(x), y0f = floorf(y);
        const float wx = x - x0f, wy = y - y0f;
        const int x0 = (int)x0f, y0 = (int)y0f;
        const int x1 = x0 + 1,   y1 = y0 + 1;
        const bool vx0 = (unsigned)x0 < 256u, vx1 = (unsigned)x1 < 256u;
        const bool vy0 = (unsigned)y0 < 256u, vy1 = (unsigned)y1 < 256u;
        const int cx0 = min(max(x0, 0), 255), cx1 = min(max(x1, 0), 255);
        const int cy0 = min(max(y0, 0), 255), cy1 = min(max(y1, 0), 255);
        off[p][0] = (cy0 << 8) + cx0;  w[p][0] = ((vx0 && vy0) ? 1.f : 0.f) * (1.f - wx) * (1.f - wy);
        off[p][1] = (cy0 << 8) + cx1;  w[p][1] = ((vx1 && vy0) ? 1.f : 0.f) * wx * (1.f - wy);
        off[p][2] = (cy1 << 8) + cx0;  w[p][2] = ((vx0 && vy1) ? 1.f : 0.f) * (1.f - wx) * wy;
        off[p][3] = (cy1 << 8) + cx1;  w[p][3] = ((vx1 && vy1) ? 1.f : 0.f) * wx * wy;
    }

    float* op = out + ((size_t)n * M + m) * Cc;
    constexpr float third = 1.0f / 3.0f;
    for (int c = 0; c < Cc; ++c) {
        float a = 0.f;
        #pragma unroll
        for (int p = 0; p < 3; ++p) {
            const float* b = planes + ((size_t)(n * 3 + p) * Cc + c) * HWPIX;
            a += w[p][0] * b[off[p][0]] + w[p][1] * b[off[p][1]]
               + w[p][2] * b[off[p][2]] + w[p][3] * b[off[p][3]];
        }
        op[c] = a * third;
    }
}

extern "C" void kernel_launch(void* const* d_in, const int* in_sizes, int n_in,
                              void* d_out, int out_size, void* d_ws, size_t ws_size,
                              hipStream_t stream)
{
    const float* planes = (const float*)d_in[0];
    const float* coords = (const float*)d_in[1];
    float* out = (float*)d_out;

    const int M = in_sizes[1] / (Nn * 3);           // 500000

    auto align256 = [](size_t x) { return (x + 255) & ~(size_t)255; };
    const size_t tpf_bytes  = align256((size_t)Nn * Pp * HWPIX * Cc * sizeof(float));  // ~100 MB
    const size_t kp_bytes   = align256((size_t)Nn * M * sizeof(unsigned));             // ~8 MB
    const size_t idx_bytes  = align256((size_t)Nn * M * sizeof(unsigned));             // ~8 MB
    const size_t hist_bytes = align256((size_t)Nn * NCELLS * sizeof(unsigned));        // 0.5 MB
    const size_t tph_bytes  = align256((size_t)Nn * Pp * HWPIX * Cc * sizeof(__half)); // ~50 MB

    if (ws_size >= tpf_bytes + kp_bytes + idx_bytes + hist_bytes) {
        char* p = (char*)d_ws;
        float*    tp   = (float*)p;    p += tpf_bytes;
        unsigned* kp   = (unsigned*)p; p += kp_bytes;
        unsigned* idx  = (unsigned*)p; p += idx_bytes;
        unsigned* hist = (unsigned*)p;

        transpose_chw_hwc<<<dim3(HWPIX / 256, Nn * Pp), 256, 0, stream>>>(planes, tp);
        zero_u32<<<(Nn * NCELLS + 255) / 256, 256, 0, stream>>>(hist, Nn * NCELLS);

        const int t8 = (M + 7) / 8;
        histpos8_kernel<<<dim3((t8 + 255) / 256, Nn), 256, 0, stream>>>(coords, hist, kp, M);
        scan_kernel<<<Nn, 1024, 0, stream>>>(hist);
        scatter8_kernel<<<dim3((t8 + 255) / 256, Nn), 256, 0, stream>>>(kp, hist, idx, M);

        const int gx  = (M * 4 + 255) / 256;   // 4 lanes per sample
        const int nwg = Nn * gx;
        triplane_gather_sorted4<<<nwg, 256, 0, stream>>>(tp, idx, coords, out, M, gx, nwg);
    } else if (ws_size >= tph_bytes) {
        __half* tp = (__half*)d_ws;
        transpose_chw_hwc_h<<<dim3(HWPIX / 256, Nn * Pp), 256, 0, stream>>>(planes, tp);
        const int gx = (M * 8 + 255) / 256;
        triplane_gather_hwc8h<<<dim3(gx, Nn), 256, 0, stream>>>(tp, coords, out, M);
    } else {
        const int gx = (M + 255) / 256;
        triplane_gather_chw<<<dim3(gx, Nn), 256, 0, stream>>>(planes, coords, out, M);
    }
}

// Round 8
// 284.150 us; speedup vs baseline: 1.4693x; 1.2926x over previous
//
#include <hip/hip_runtime.h>
#include <hip/hip_fp16.h>

// Tri-plane importance-renderer sampling.
// planes: [N=4][P=3][C=32][H=256][W=256] f32
// coords: [N][M=500000][3] f32, directions unused.
// out:    [N][M][C] f32  = mean over P of bilinear samples (zeros padding,
//                          align_corners=False).
// Plane->grid mapping (from inv(_PLANES)): p0:(cx,cy)  p1:(cx,cz)  p2:(cz,cx)
//
// R7 insight: f32 planes re-bloated the random-access footprint (FETCH 98MB
// -> 320MB, gather 156 -> 206us) even though VALU dropped 61% -> 22%.
// R8: fp16 planes (proven compulsory-fetch) + 4-lane gather with packed-fp16
// per-plane accumulation (cuts VALU ~2x vs R6), and an atomic-FREE sort:
// block-local LDS counting sort over 4096 coarse Morton cells
// (S1 hist -> S2a per-cell block prefix -> S2b cell scan -> S3 rank scatter).

constexpr int Cc = 32, Hh = 256, Ww = 256, Pp = 3, Nn = 4;
constexpr int HWPIX = Hh * Ww;   // 65536
constexpr int NCO   = 4096;      // 16^3 coarse cells
constexpr int CB    = 2048;      // samples per sort block

__device__ inline unsigned spread3(unsigned x) {
    x &= 0x3FFu;
    x = (x | (x << 16)) & 0x030000FFu;
    x = (x | (x << 8))  & 0x0300F00Fu;
    x = (x | (x << 4))  & 0x030C30C3u;
    x = (x | (x << 2))  & 0x09249249u;
    return x;
}
// 12-bit Morton key from 4 bits/axis.
__device__ inline unsigned coarse_key(float cx, float cy, float cz) {
    const int a = min(max((int)((cx + 1.0f) * 8.0f), 0), 15);
    const int b = min(max((int)((cy + 1.0f) * 8.0f), 0), 15);
    const int c = min(max((int)((cz + 1.0f) * 8.0f), 0), 15);
    return spread3((unsigned)a) | (spread3((unsigned)b) << 1) | (spread3((unsigned)c) << 2);
}

// ---------------------------------------------------------------------------
// Pass 1: transpose+convert [slice][C][HW] f32 -> [slice][HW][C] fp16.
// ---------------------------------------------------------------------------
__global__ __launch_bounds__(256) void transpose_chw_hwc_h(
    const float* __restrict__ in, __half* __restrict__ out)
{
    __shared__ float lds[Cc * 257];
    const int slice = blockIdx.y;
    const int pix0  = blockIdx.x * 256;
    const int t     = threadIdx.x;

    const float* src = in + (size_t)slice * Cc * HWPIX + pix0 + t;
    #pragma unroll
    for (int c = 0; c < Cc; ++c)
        lds[c * 257 + t] = src[(size_t)c * HWPIX];
    __syncthreads();

    uint4* dst = reinterpret_cast<uint4*>(
        out + (size_t)slice * HWPIX * Cc + (size_t)pix0 * Cc);
    #pragma unroll
    for (int k = 0; k < 4; ++k) {
        const int idx = k * 256 + t;
        const int pix = idx >> 2;
        const int c0  = (idx & 3) * 8;
        unsigned r[4];
        #pragma unroll
        for (int j = 0; j < 4; ++j) {
            const __half h0 = __float2half(lds[(c0 + 2 * j + 0) * 257 + pix]);
            const __half h1 = __float2half(lds[(c0 + 2 * j + 1) * 257 + pix]);
            r[j] = (unsigned)__half_as_ushort(h0)
                 | ((unsigned)__half_as_ushort(h1) << 16);
        }
        dst[idx] = make_uint4(r[0], r[1], r[2], r[3]);
    }
}

// ---------------------------------------------------------------------------
// Atomic-free counting sort (LDS only).
// bh layout: [n][block][NCO].  tot/cellbase: [n][NCO].
// ---------------------------------------------------------------------------
__global__ __launch_bounds__(256) void block_hist(
    const float* __restrict__ coords, unsigned* __restrict__ bh, int M, int nb)
{
    __shared__ unsigned h[NCO];
    const int n = blockIdx.y, b = blockIdx.x, t = threadIdx.x;
    #pragma unroll
    for (int k = 0; k < NCO / 256; ++k) h[k * 256 + t] = 0u;
    __syncthreads();

    const int base = b * CB;
    for (int j = t; j < CB; j += 256) {
        const int m = base + j;
        if (m < M) {
            const float* cp = coords + ((size_t)n * M + m) * 3;
            atomicAdd(&h[coarse_key(cp[0], cp[1], cp[2])], 1u);  // LDS atomic
        }
    }
    __syncthreads();
    unsigned* dst = bh + ((size_t)n * nb + b) * NCO;
    #pragma unroll
    for (int k = 0; k < NCO / 256; ++k) dst[k * 256 + t] = h[k * 256 + t];
}

// Per cell: exclusive prefix over blocks (in place), total -> tot[n][cell].
__global__ __launch_bounds__(256) void col_prefix(
    unsigned* __restrict__ bh, unsigned* __restrict__ tot, int nb)
{
    const int n = blockIdx.y;
    const int c = blockIdx.x * 256 + threadIdx.x;
    unsigned* p = bh + (size_t)n * nb * NCO + c;
    unsigned run = 0;
    for (int b = 0; b < nb; ++b) {
        const unsigned v = p[(size_t)b * NCO];
        p[(size_t)b * NCO] = run;
        run += v;
    }
    tot[n * NCO + c] = run;
}

// Exclusive scan of the 4096 cell totals (in place), one block per n.
__global__ __launch_bounds__(1024) void cell_scan(unsigned* __restrict__ tot)
{
    __shared__ unsigned lds[1024];
    unsigned* h = tot + (size_t)blockIdx.x * NCO;
    const int t = threadIdx.x;
    unsigned v[4];
    unsigned s = 0;
    #pragma unroll
    for (int i = 0; i < 4; ++i) { v[i] = h[t * 4 + i]; s += v[i]; }
    lds[t] = s;
    __syncthreads();
    for (int d = 1; d < 1024; d <<= 1) {
        const unsigned add = (t >= d) ? lds[t - d] : 0u;
        __syncthreads();
        lds[t] += add;
        __syncthreads();
    }
    unsigned base = (t > 0) ? lds[t - 1] : 0u;
    #pragma unroll
    for (int i = 0; i < 4; ++i) { const unsigned tmp = v[i]; h[t * 4 + i] = base; base += tmp; }
}

// slot = cellbase[cell] + blockbase[cell] + LDS rank.  Valid permutation;
// within-cell order irrelevant for correctness (each sample writes slot m).
__global__ __launch_bounds__(256) void block_scatter(
    const float* __restrict__ coords, const unsigned* __restrict__ bh,
    const unsigned* __restrict__ cellbase, unsigned* __restrict__ idx,
    int M, int nb)
{
    __shared__ unsigned h[NCO];
    const int n = blockIdx.y, b = blockIdx.x, t = threadIdx.x;
    #pragma unroll
    for (int k = 0; k < NCO / 256; ++k) h[k * 256 + t] = 0u;
    __syncthreads();

    const unsigned* myrow = bh + ((size_t)n * nb + b) * NCO;
    const int base = b * CB;
    for (int j = t; j < CB; j += 256) {
        const int m = base + j;
        if (m < M) {
            const float* cp = coords + ((size_t)n * M + m) * 3;
            const unsigned k = coarse_key(cp[0], cp[1], cp[2]);
            const unsigned r = atomicAdd(&h[k], 1u);     // LDS rank
            const unsigned slot = cellbase[n * NCO + k] + myrow[k] + r;
            idx[(size_t)n * M + slot] = (unsigned)m;
        }
    }
}

// ---------------------------------------------------------------------------
// Gather in coarse-Morton order. FOUR lanes per sample, 8 fp16 channels each
// (one uint4 per corner). Per-plane packed-fp16 accumulation (__hfma2),
// cross-plane combine in f32. Bijective XCD-chunked swizzle.
// ---------------------------------------------------------------------------
__global__ __launch_bounds__(256) void triplane_gather4h(
    const __half* __restrict__ tp, const unsigned* __restrict__ idx,
    const float* __restrict__ coords, float* __restrict__ out,
    int M, int gx, int nwg)
{
    int bid = blockIdx.x;
    {   // bijective chunked XCD swizzle (m204 form)
        const int q = nwg >> 3, r = nwg & 7;
        const int xcd = bid & 7, i = bid >> 3;
        bid = (xcd < r ? xcd * (q + 1) : r * (q + 1) + (xcd - r) * q) + i;
    }
    const int n  = bid / gx;
    const int bx = bid - n * gx;
    const int gid  = bx * 256 + threadIdx.x;
    const int s    = gid >> 2;
    const int quad = gid & 3;            // 8-channel group
    if (s >= M) return;

    const int m = (int)idx[(size_t)n * M + s];
    const float* cp = coords + ((size_t)n * M + m) * 3;
    const float cx = cp[0], cy = cp[1], cz = cp[2];

    const uint4* addr[12];
    __half2 wh[12];

    #pragma unroll
    for (int p = 0; p < 3; ++p) {
        const float gxc = (p == 2) ? cz : cx;
        const float gyc = (p == 0) ? cy : ((p == 1) ? cz : cx);
        // exact reference op order: ((g+1)*S - 1) * 0.5
        const float x = ((gxc + 1.0f) * 256.0f - 1.0f) * 0.5f;
        const float y = ((gyc + 1.0f) * 256.0f - 1.0f) * 0.5f;
        const float x0f = floorf(x), y0f = floorf(y);
        const float wx = x - x0f, wy = y - y0f;
        const int x0 = (int)x0f, y0 = (int)y0f;
        const int x1 = x0 + 1,   y1 = y0 + 1;
        const bool vx0 = (unsigned)x0 < 256u;
        const bool vx1 = (unsigned)x1 < 256u;
        const bool vy0 = (unsigned)y0 < 256u;
        const bool vy1 = (unsigned)y1 < 256u;
        const int cx0 = min(max(x0, 0), 255), cx1 = min(max(x1, 0), 255);
        const int cy0 = min(max(y0, 0), 255), cy1 = min(max(y1, 0), 255);

        const float w00 = ((vx0 && vy0) ? 1.f : 0.f) * (1.f - wx) * (1.f - wy);
        const float w10 = ((vx1 && vy0) ? 1.f : 0.f) * wx * (1.f - wy);
        const float w01 = ((vx0 && vy1) ? 1.f : 0.f) * (1.f - wx) * wy;
        const float w11 = ((vx1 && vy1) ? 1.f : 0.f) * wx * wy;
        wh[p * 4 + 0] = __float2half2_rn(w00);
        wh[p * 4 + 1] = __float2half2_rn(w10);
        wh[p * 4 + 2] = __float2half2_rn(w01);
        wh[p * 4 + 3] = __float2half2_rn(w11);

        // pixel record = 32 halves = 4 uint4; lane reads uint4 #quad.
        const uint4* base = reinterpret_cast<const uint4*>(
            tp + (size_t)(n * 3 + p) * HWPIX * Cc);
        addr[p * 4 + 0] = base + (size_t)((cy0 << 8) + cx0) * 4 + quad;
        addr[p * 4 + 1] = base + (size_t)((cy0 << 8) + cx1) * 4 + quad;
        addr[p * 4 + 2] = base + (size_t)((cy1 << 8) + cx0) * 4 + quad;
        addr[p * 4 + 3] = base + (size_t)((cy1 << 8) + cx1) * 4 + quad;
    }

    // Issue all 12 independent 16B loads.
    uint4 rv[12];
    #pragma unroll
    for (int j = 0; j < 12; ++j) rv[j] = *addr[j];

    float accx[8];
    #pragma unroll
    for (int i = 0; i < 8; ++i) accx[i] = 0.f;

    // Per plane: packed fp16 bilinear accumulate (4 corners), then f32 add.
    #pragma unroll
    for (int p = 0; p < 3; ++p) {
        __half2 a0 = __float2half2_rn(0.f), a1 = a0, a2 = a0, a3 = a0;
        #pragma unroll
        for (int c = 0; c < 4; ++c) {
            const uint4 v = rv[p * 4 + c];
            const __half2 w = wh[p * 4 + c];
            a0 = __hfma2(*reinterpret_cast<const __half2*>(&v.x), w, a0);
            a1 = __hfma2(*reinterpret_cast<const __half2*>(&v.y), w, a1);
            a2 = __hfma2(*reinterpret_cast<const __half2*>(&v.z), w, a2);
            a3 = __hfma2(*reinterpret_cast<const __half2*>(&v.w), w, a3);
        }
        const float2 f0 = __half22float2(a0);
        const float2 f1 = __half22float2(a1);
        const float2 f2 = __half22float2(a2);
        const float2 f3 = __half22float2(a3);
        accx[0] += f0.x; accx[1] += f0.y;
        accx[2] += f1.x; accx[3] += f1.y;
        accx[4] += f2.x; accx[5] += f2.y;
        accx[6] += f3.x; accx[7] += f3.y;
    }

    constexpr float third = 1.0f / 3.0f;
    float4 o0, o1;
    o0.x = accx[0] * third; o0.y = accx[1] * third;
    o0.z = accx[2] * third; o0.w = accx[3] * third;
    o1.x = accx[4] * third; o1.y = accx[5] * third;
    o1.z = accx[6] * third; o1.w = accx[7] * third;

    float4* op = reinterpret_cast<float4*>(out + ((size_t)n * M + m) * Cc);
    op[quad * 2 + 0] = o0;
    op[quad * 2 + 1] = o1;
}

// ---------------------------------------------------------------------------
// Mid tier (ws fits fp16 planes only): unsorted fp16 gather (R3 kernel).
// ---------------------------------------------------------------------------
__global__ __launch_bounds__(256) void triplane_gather_hwc8h(
    const __half* __restrict__ tp, const float* __restrict__ coords,
    float* __restrict__ out, int M)
{
    const int gid   = blockIdx.x * 256 + threadIdx.x;
    const int m     = gid >> 3;
    const int chunk = gid & 7;
    const int n     = blockIdx.y;
    if (m >= M) return;

    const float* cp = coords + ((size_t)n * M + m) * 3;
    const float cx = cp[0], cy = cp[1], cz = cp[2];

    const uint2* addr[12];
    float w[12];

    #pragma unroll
    for (int p = 0; p < 3; ++p) {
        const float gxc = (p == 2) ? cz : cx;
        const float gyc = (p == 0) ? cy : ((p == 1) ? cz : cx);
        const float x = ((gxc + 1.0f) * 256.0f - 1.0f) * 0.5f;
        const float y = ((gyc + 1.0f) * 256.0f - 1.0f) * 0.5f;
        const float x0f = floorf(x), y0f = floorf(y);
        const float wx = x - x0f, wy = y - y0f;
        const int x0 = (int)x0f, y0 = (int)y0f;
        const int x1 = x0 + 1,   y1 = y0 + 1;
        const bool vx0 = (unsigned)x0 < 256u;
        const bool vx1 = (unsigned)x1 < 256u;
        const bool vy0 = (unsigned)y0 < 256u;
        const bool vy1 = (unsigned)y1 < 256u;
        const int cx0 = min(max(x0, 0), 255), cx1 = min(max(x1, 0), 255);
        const int cy0 = min(max(y0, 0), 255), cy1 = min(max(y1, 0), 255);

        w[p * 4 + 0] = ((vx0 && vy0) ? 1.f : 0.f) * (1.f - wx) * (1.f - wy);
        w[p * 4 + 1] = ((vx1 && vy0) ? 1.f : 0.f) * wx * (1.f - wy);
        w[p * 4 + 2] = ((vx0 && vy1) ? 1.f : 0.f) * (1.f - wx) * wy;
        w[p * 4 + 3] = ((vx1 && vy1) ? 1.f : 0.f) * wx * wy;

        const uint2* base = reinterpret_cast<const uint2*>(
            tp + (size_t)(n * 3 + p) * HWPIX * Cc);
        addr[p * 4 + 0] = base + (size_t)((cy0 << 8) + cx0) * 8 + chunk;
        addr[p * 4 + 1] = base + (size_t)((cy0 << 8) + cx1) * 8 + chunk;
        addr[p * 4 + 2] = base + (size_t)((cy1 << 8) + cx0) * 8 + chunk;
        addr[p * 4 + 3] = base + (size_t)((cy1 << 8) + cx1) * 8 + chunk;
    }

    uint2 rv[12];
    #pragma unroll
    for (int j = 0; j < 12; ++j) rv[j] = *addr[j];

    float4 acc = make_float4(0.f, 0.f, 0.f, 0.f);
    #pragma unroll
    for (int j = 0; j < 12; ++j) {
        const __half2 h0 = *reinterpret_cast<const __half2*>(&rv[j].x);
        const __half2 h1 = *reinterpret_cast<const __half2*>(&rv[j].y);
        const float2 f0 = __half22float2(h0);
        const float2 f1 = __half22float2(h1);
        acc.x += w[j] * f0.x;
        acc.y += w[j] * f0.y;
        acc.z += w[j] * f1.x;
        acc.w += w[j] * f1.y;
    }

    constexpr float third = 1.0f / 3.0f;
    acc.x *= third; acc.y *= third; acc.z *= third; acc.w *= third;

    float4* op = reinterpret_cast<float4*>(out + ((size_t)n * M + m) * Cc);
    op[chunk] = acc;
}

// ---------------------------------------------------------------------------
// Fallback (no workspace): gather straight from [C][H][W] f32 layout.
// ---------------------------------------------------------------------------
__global__ __launch_bounds__(256) void triplane_gather_chw(
    const float* __restrict__ planes, const float* __restrict__ coords,
    float* __restrict__ out, int M)
{
    const int m = blockIdx.x * 256 + threadIdx.x;
    const int n = blockIdx.y;
    if (m >= M) return;

    const float* cp = coords + ((size_t)n * M + m) * 3;
    const float cx = cp[0], cy = cp[1], cz = cp[2];

    int   off[3][4];
    float w[3][4];
    #pragma unroll
    for (int p = 0; p < 3; ++p) {
        const float gxc = (p == 2) ? cz : cx;
        const float gyc = (p == 0) ? cy : ((p == 1) ? cz : cx);
        const float x = ((gxc + 1.0f) * 256.0f - 1.0f) * 0.5f;
        const float y = ((gyc + 1.0f) * 256.0f - 1.0f) * 0.5f;
        const float x0f = floorf(x), y0f = floorf(y);
        const float wx = x - x0f, wy = y - y0f;
        const int x0 = (int)x0f, y0 = (int)y0f;
        const int x1 = x0 + 1,   y1 = y0 + 1;
        const bool vx0 = (unsigned)x0 < 256u, vx1 = (unsigned)x1 < 256u;
        const bool vy0 = (unsigned)y0 < 256u, vy1 = (unsigned)y1 < 256u;
        const int cx0 = min(max(x0, 0), 255), cx1 = min(max(x1, 0), 255);
        const int cy0 = min(max(y0, 0), 255), cy1 = min(max(y1, 0), 255);
        off[p][0] = (cy0 << 8) + cx0;  w[p][0] = ((vx0 && vy0) ? 1.f : 0.f) * (1.f - wx) * (1.f - wy);
        off[p][1] = (cy0 << 8) + cx1;  w[p][1] = ((vx1 && vy0) ? 1.f : 0.f) * wx * (1.f - wy);
        off[p][2] = (cy1 << 8) + cx0;  w[p][2] = ((vx0 && vy1) ? 1.f : 0.f) * (1.f - wx) * wy;
        off[p][3] = (cy1 << 8) + cx1;  w[p][3] = ((vx1 && vy1) ? 1.f : 0.f) * wx * wy;
    }

    float* op = out + ((size_t)n * M + m) * Cc;
    constexpr float third = 1.0f / 3.0f;
    for (int c = 0; c < Cc; ++c) {
        float a = 0.f;
        #pragma unroll
        for (int p = 0; p < 3; ++p) {
            const float* b = planes + ((size_t)(n * 3 + p) * Cc + c) * HWPIX;
            a += w[p][0] * b[off[p][0]] + w[p][1] * b[off[p][1]]
               + w[p][2] * b[off[p][2]] + w[p][3] * b[off[p][3]];
        }
        op[c] = a * third;
    }
}

extern "C" void kernel_launch(void* const* d_in, const int* in_sizes, int n_in,
                              void* d_out, int out_size, void* d_ws, size_t ws_size,
                              hipStream_t stream)
{
    const float* planes = (const float*)d_in[0];
    const float* coords = (const float*)d_in[1];
    float* out = (float*)d_out;

    const int M  = in_sizes[1] / (Nn * 3);          // 500000
    const int nb = (M + CB - 1) / CB;               // sort blocks per n

    auto align256 = [](size_t x) { return (x + 255) & ~(size_t)255; };
    const size_t tph_bytes = align256((size_t)Nn * Pp * HWPIX * Cc * sizeof(__half)); // ~50 MB
    const size_t idx_bytes = align256((size_t)Nn * M * sizeof(unsigned));             // ~8 MB
    const size_t bh_bytes  = align256((size_t)Nn * nb * NCO * sizeof(unsigned));      // ~16 MB
    const size_t tot_bytes = align256((size_t)Nn * NCO * sizeof(unsigned));           // 64 KB

    if (ws_size >= tph_bytes + idx_bytes + bh_bytes + tot_bytes) {
        char* p = (char*)d_ws;
        __half*   tp  = (__half*)p;    p += tph_bytes;
        unsigned* idx = (unsigned*)p;  p += idx_bytes;
        unsigned* bh  = (unsigned*)p;  p += bh_bytes;
        unsigned* tot = (unsigned*)p;

        transpose_chw_hwc_h<<<dim3(HWPIX / 256, Nn * Pp), 256, 0, stream>>>(planes, tp);
        block_hist<<<dim3(nb, Nn), 256, 0, stream>>>(coords, bh, M, nb);
        col_prefix<<<dim3(NCO / 256, Nn), 256, 0, stream>>>(bh, tot, nb);
        cell_scan<<<Nn, 1024, 0, stream>>>(tot);
        block_scatter<<<dim3(nb, Nn), 256, 0, stream>>>(coords, bh, tot, idx, M, nb);

        const int gx  = (M * 4 + 255) / 256;   // 4 lanes per sample
        const int nwg = Nn * gx;
        triplane_gather4h<<<nwg, 256, 0, stream>>>(tp, idx, coords, out, M, gx, nwg);
    } else if (ws_size >= tph_bytes) {
        __half* tp = (__half*)d_ws;
        transpose_chw_hwc_h<<<dim3(HWPIX / 256, Nn * Pp), 256, 0, stream>>>(planes, tp);
        const int gx = (M * 8 + 255) / 256;
        triplane_gather_hwc8h<<<dim3(gx, Nn), 256, 0, stream>>>(tp, coords, out, M);
    } else {
        const int gx = (M + 255) / 256;
        triplane_gather_chw<<<dim3(gx, Nn), 256, 0, stream>>>(planes, coords, out, M);
    }
}